// Round 4
// baseline (272.245 us; speedup 1.0000x reference)
//
#include <hip/hip_runtime.h>
#include <math.h>

// N = 160000 = 256 * 625; four-step FFT.
// f1: per column n1: in-place DIF-625 (sign -), digit-reversed epilogue -> G[k2][n1] * W^{n1 k2}
// fi: per k2-row: fwd DIF-256 (sign -) with last stage kept in registers; per band:
//     mask in registers -> inv DIT-256 (sign +) -> twiddle -> H[n1][k2]
// i2: per column n1: in-place DIF-625 (sign +), last stage fused into hop-energy
//     accumulation (output order digit-reversed; n2 recovered via base-5 rev)
constexpr int L      = 160000;
constexpr int BATCH  = 8;
constexpr int NB     = 8;
constexpr int NHOPS  = 156;
constexpr int NCHUNK = 155;
constexpr float TWO_PI = 6.28318530717958647692f;

__device__ __forceinline__ float2 cmulf(float2 a, float2 b) {
  return make_float2(a.x * b.x - a.y * b.y, a.x * b.y + a.y * b.x);
}

template <int SIGN>
__device__ __forceinline__ float2 twld(const float2* __restrict__ W, int idx) {
  float2 t = W[idx];
  if constexpr (SIGN > 0) t.y = -t.y;
  return t;
}

// plain DFT-4 / DFT-5 matrices, out[k] = sum_r in[r] * e^{SIGN*2pi i k r / R}
template <int SIGN>
__device__ __forceinline__ void bf4s(float2* v) {
  float2 t0 = make_float2(v[0].x + v[2].x, v[0].y + v[2].y);
  float2 t1 = make_float2(v[0].x - v[2].x, v[0].y - v[2].y);
  float2 t2 = make_float2(v[1].x + v[3].x, v[1].y + v[3].y);
  float2 t3 = make_float2(v[1].x - v[3].x, v[1].y - v[3].y);
  v[0] = make_float2(t0.x + t2.x, t0.y + t2.y);
  v[2] = make_float2(t0.x - t2.x, t0.y - t2.y);
  if constexpr (SIGN < 0) {
    v[1] = make_float2(t1.x + t3.y, t1.y - t3.x);
    v[3] = make_float2(t1.x - t3.y, t1.y + t3.x);
  } else {
    v[1] = make_float2(t1.x - t3.y, t1.y + t3.x);
    v[3] = make_float2(t1.x + t3.y, t1.y - t3.x);
  }
}

template <int SIGN>
__device__ __forceinline__ void bf5s(float2* v) {
  const float c1 = 0.30901699437494745f, s1 = 0.9510565162951535f;
  const float c2 = -0.8090169943749475f, s2 = 0.5877852522924731f;
  float2 t1 = make_float2(v[1].x + v[4].x, v[1].y + v[4].y);
  float2 t3 = make_float2(v[1].x - v[4].x, v[1].y - v[4].y);
  float2 t2 = make_float2(v[2].x + v[3].x, v[2].y + v[3].y);
  float2 t4 = make_float2(v[2].x - v[3].x, v[2].y - v[3].y);
  float2 a = make_float2(v[0].x + c1 * t1.x + c2 * t2.x, v[0].y + c1 * t1.y + c2 * t2.y);
  float2 b = make_float2(s1 * t3.x + s2 * t4.x, s1 * t3.y + s2 * t4.y);
  float2 c = make_float2(v[0].x + c2 * t1.x + c1 * t2.x, v[0].y + c2 * t1.y + c1 * t2.y);
  float2 d = make_float2(s2 * t3.x - s1 * t4.x, s2 * t3.y - s1 * t4.y);
  v[0] = make_float2(v[0].x + t1.x + t2.x, v[0].y + t1.y + t2.y);
  if constexpr (SIGN < 0) {
    v[1] = make_float2(a.x + b.y, a.y - b.x);
    v[4] = make_float2(a.x - b.y, a.y + b.x);
    v[2] = make_float2(c.x + d.y, c.y - d.x);
    v[3] = make_float2(c.x - d.y, c.y + d.x);
  } else {
    v[1] = make_float2(a.x - b.y, a.y + b.x);
    v[4] = make_float2(a.x + b.y, a.y - b.x);
    v[2] = make_float2(c.x - d.y, c.y + d.x);
    v[3] = make_float2(c.x + d.y, c.y - d.x);
  }
}

// apply y[r] *= t1^r for r=1..R-1 (chained powers; W[0]=1 exact)
template <int R>
__device__ __forceinline__ void twchain(float2* v, float2 t1) {
  float2 t = t1;
  v[1] = cmulf(v[1], t);
#pragma unroll
  for (int r = 2; r < R; ++r) { t = cmulf(t, t1); v[r] = cmulf(v[r], t); }
}

// ---------- in-place DIF-625 stages 1..3 (per-wave private; lgkmcnt orders same-wave LDS) ----------
template <int SIGN>
__device__ __forceinline__ void dif625_s123(float2* a, int ln, const float2* __restrict__ W) {
  // stage 1: j<125, stride 125, tw w625^{jr} (step 256), applied post-butterfly
#pragma unroll
  for (int it = 0; it < 2; ++it) {
    int j = ln + it * 64;
    if (j < 125) {
      float2 v[5];
#pragma unroll
      for (int r = 0; r < 5; ++r) v[r] = a[j + 125 * r];
      bf5s<SIGN>(v);
      twchain<5>(v, twld<SIGN>(W, j * 256));
#pragma unroll
      for (int r = 0; r < 5; ++r) a[j + 125 * r] = v[r];
    }
  }
  // stage 2: 5 blocks of 125: B=idx/25, j=idx%25, stride 25, tw w125^{jr} (step 1280)
#pragma unroll
  for (int it = 0; it < 2; ++it) {
    int idx = ln + it * 64;
    if (idx < 125) {
      int B = idx / 25, j = idx - 25 * B;
      int base = 125 * B + j;
      float2 v[5];
#pragma unroll
      for (int r = 0; r < 5; ++r) v[r] = a[base + 25 * r];
      bf5s<SIGN>(v);
      twchain<5>(v, twld<SIGN>(W, j * 1280));
#pragma unroll
      for (int r = 0; r < 5; ++r) a[base + 25 * r] = v[r];
    }
  }
  // stage 3: 25 blocks of 25: B=idx/5, j=idx%5, stride 5, tw w25^{jr} (step 6400)
#pragma unroll
  for (int it = 0; it < 2; ++it) {
    int idx = ln + it * 64;
    if (idx < 125) {
      int B = idx / 5, j = idx - 5 * B;
      int base = 25 * B + j;
      float2 v[5];
#pragma unroll
      for (int r = 0; r < 5; ++r) v[r] = a[base + 5 * r];
      bf5s<SIGN>(v);
      twchain<5>(v, twld<SIGN>(W, j * 6400));
#pragma unroll
      for (int r = 0; r < 5; ++r) a[base + 5 * r] = v[r];
    }
  }
}

__device__ __forceinline__ int rev3_5(int q) {  // reverse 3 base-5 digits, q<125
  int q5 = q / 5, q25 = q / 25;
  int d0 = q - 5 * q5, d1 = q5 - 5 * q25;
  return 25 * d0 + 5 * d1 + q25;
}

__device__ __forceinline__ int rev4_5(int k) {  // reverse 4 base-5 digits, k<625
  int k5 = k / 5, k25 = k / 125;
  int d0 = k - 5 * k5;
  int k55 = k5 / 5;
  int d1 = k5 - 5 * k55, d2 = k55 - 5 * k25;
  return 125 * d0 + 25 * d1 + 5 * d2 + k25;
}

__device__ __forceinline__ int pad(int i) { return i + (i >> 5); }  // LDS anti-conflict pad

// ---------- setup: W[k] = e^{-2pi i k/L} ----------
__global__ __launch_bounds__(256) void setup_kernel(float2* __restrict__ W) {
  int k = blockIdx.x * 256 + threadIdx.x;
  if (k < L) {
    float s, c;
    sincosf(-TWO_PI * ((float)k / (float)L), &s, &c);
    W[k] = make_float2(c, s);
  }
}

// ---------- F1: pack w+i*o, in-place DIF-625 per column, epilogue un-reverses -> G ----------
__global__ __launch_bounds__(256) void f1_kernel(const float* __restrict__ win,
                                                 const float* __restrict__ oin,
                                                 float2* __restrict__ G,
                                                 const float2* __restrict__ W) {
  __shared__ float2 A[4 * 625];   // 20 KB -> 8 blocks/CU
  int blk = blockIdx.x;
  int sig = blk >> 6, g = blk & 63;
  int n1base = g * 4;
  int tid = threadIdx.x;
  const float* wp = win + (size_t)sig * L;
  const float* op = oin + (size_t)sig * L;
  for (int idx = tid; idx < 2500; idx += 256) {
    int n2 = idx >> 2, cc = idx & 3;
    int n = (n2 << 8) + n1base + cc;
    A[cc * 625 + n2] = make_float2(wp[n], op[n]);
  }
  __syncthreads();
  int wv = tid >> 6, ln = tid & 63;
  float2* a = A + wv * 625;
  dif625_s123<-1>(a, ln, W);
  // stage 4: 125 blocks of 5, no twiddle, write back
#pragma unroll
  for (int it = 0; it < 2; ++it) {
    int q = ln + it * 64;
    if (q < 125) {
      float2 v[5];
#pragma unroll
      for (int r = 0; r < 5; ++r) v[r] = a[5 * q + r];
      bf5s<-1>(v);
#pragma unroll
      for (int r = 0; r < 5; ++r) a[5 * q + r] = v[r];
    }
  }
  __syncthreads();
  for (int idx = tid; idx < 2500; idx += 256) {
    int k2 = idx >> 2, cc = idx & 3;
    int n1 = n1base + cc;
    float2 val = A[cc * 625 + rev4_5(k2)];     // position rev(k2) holds X[k2]
    G[(size_t)sig * L + k2 * 256 + n1] = cmulf(val, W[n1 * k2]);
  }
}

// ---------- FI: fused fwd-256-DIF + per-band masked inv-256-DIT -> H[n1][k2] ----------
__global__ __launch_bounds__(256) void fi_kernel(const float2* __restrict__ G,
                                                 float2* __restrict__ H,
                                                 const float2* __restrict__ W) {
  __shared__ float2 A[4 * 264];   // padded rows: pad(255)=262 < 264
  int blk = blockIdx.x;
  int sig = blk / 157, gr = blk % 157;
  int k2base = gr * 4;
  int tid = threadIdx.x;
  int wv = tid >> 6, ln = tid & 63;
  int k2 = k2base + wv;
  bool valid = (k2 < 625);
  float2* a = A + wv * 264;

  // load own row (coalesced 2 KB per wave)
#pragma unroll
  for (int r = 0; r < 4; ++r) {
    int k1 = ln + 64 * r;
    float2 val = make_float2(0.0f, 0.0f);
    if (valid) val = G[(size_t)sig * L + k2 * 256 + k1];
    a[pad(k1)] = val;
  }
  // forward DIF-256 (sign -): stages A,B,C in LDS, stage D in registers
  {  // stage A: j<64, stride 64, tw w256^{jr} (step 625)
    float2 v[4];
#pragma unroll
    for (int r = 0; r < 4; ++r) v[r] = a[pad(ln + 64 * r)];
    bf4s<-1>(v);
    twchain<4>(v, W[ln * 625]);
#pragma unroll
    for (int r = 0; r < 4; ++r) a[pad(ln + 64 * r)] = v[r];
  }
  {  // stage B: 4 blocks of 64: B=ln>>4, j=ln&15, stride 16, tw w64^{jr} (step 2500)
    int B = ln >> 4, j = ln & 15, base = 64 * B + j;
    float2 v[4];
#pragma unroll
    for (int r = 0; r < 4; ++r) v[r] = a[pad(base + 16 * r)];
    bf4s<-1>(v);
    twchain<4>(v, W[j * 2500]);
#pragma unroll
    for (int r = 0; r < 4; ++r) a[pad(base + 16 * r)] = v[r];
  }
  {  // stage C: 16 blocks of 16: B=ln>>2, j=ln&3, stride 4, tw w16^{jr} (step 10000)
    int B = ln >> 2, j = ln & 3, base = 16 * B + j;
    float2 v[4];
#pragma unroll
    for (int r = 0; r < 4; ++r) v[r] = a[pad(base + 4 * r)];
    bf4s<-1>(v);
    twchain<4>(v, W[j * 10000]);
#pragma unroll
    for (int r = 0; r < 4; ++r) a[pad(base + 4 * r)] = v[r];
  }
  // stage D: 64 blocks of 4 at positions 4*ln+r -> keep in registers
  float2 xr[4];
  int bnd[4];
#pragma unroll
  for (int r = 0; r < 4; ++r) xr[r] = a[pad(4 * ln + r)];
  bf4s<-1>(xr);
  {
    int base_rev = 16 * (ln & 3) + 4 * ((ln >> 2) & 3) + (ln >> 4);
#pragma unroll
    for (int r = 0; r < 4; ++r) {
      int k1 = 64 * r + base_rev;              // rev4(4*ln+r)
      int bin = 625 * k1 + k2;
      int m = min(bin, L - bin);
      bnd[r] = (m == 0) ? (NB - 1) : (m - 1) / 10000;
    }
  }

  // per band: masked inverse DIT-256 (sign +), twiddle, store
  for (int b = 0; b < NB; ++b) {
    {  // stage 1: positions 4*ln+r from registers, no twiddle
      float2 v[4];
#pragma unroll
      for (int r = 0; r < 4; ++r)
        v[r] = (bnd[r] == b) ? xr[r] : make_float2(0.0f, 0.0f);
      bf4s<1>(v);
#pragma unroll
      for (int r = 0; r < 4; ++r) a[pad(4 * ln + r)] = v[r];
    }
    {  // stage 2: 16 blocks of 16: q=ln>>2, j=ln&3, stride 4, pre-tw conj w16^{jr}
      int q = ln >> 2, j = ln & 3, base = 16 * q + j;
      float2 v[4];
#pragma unroll
      for (int r = 0; r < 4; ++r) v[r] = a[pad(base + 4 * r)];
      twchain<4>(v, twld<1>(W, j * 10000));
      bf4s<1>(v);
#pragma unroll
      for (int r = 0; r < 4; ++r) a[pad(base + 4 * r)] = v[r];
    }
    {  // stage 3: 4 blocks of 64: q=ln>>4, j=ln&15, stride 16, pre-tw conj w64^{jr}
      int q = ln >> 4, j = ln & 15, base = 64 * q + j;
      float2 v[4];
#pragma unroll
      for (int r = 0; r < 4; ++r) v[r] = a[pad(base + 16 * r)];
      twchain<4>(v, twld<1>(W, j * 2500));
      bf4s<1>(v);
#pragma unroll
      for (int r = 0; r < 4; ++r) a[pad(base + 16 * r)] = v[r];
    }
    {  // stage 4: positions j+64r, pre-tw conj w256^{jr} -> natural order y[n1]
      int j = ln;
      float2 v[4];
#pragma unroll
      for (int r = 0; r < 4; ++r) v[r] = a[pad(j + 64 * r)];
      twchain<4>(v, twld<1>(W, j * 625));
      bf4s<1>(v);
#pragma unroll
      for (int r = 0; r < 4; ++r) a[pad(j + 64 * r)] = v[r];
    }
    __syncthreads();
    // cooperative epilogue: 32-B-chunked H writes
    size_t obase = (size_t)(sig * NB + b) * L;
    for (int idx = tid; idx < 1024; idx += 256) {
      int cc = idx & 3, n1 = idx >> 2;
      int k2e = k2base + cc;
      if (k2e < 625) {
        float2 val = A[cc * 264 + pad(n1)];
        float2 t = W[n1 * k2e];
        t.y = -t.y;
        H[obase + (size_t)n1 * 625 + k2e] = cmulf(val, t);
      }
    }
    __syncthreads();
  }
}

// ---------- I2: in-place DIF-625 (sign +) + register-fused hop energies ----------
__global__ __launch_bounds__(256) void i2_kernel(const float2* __restrict__ H,
                                                 float* __restrict__ E,
                                                 const float2* __restrict__ W) {
  __shared__ float2 A[4 * 625];      // 20000 B
  __shared__ float P[2 * NHOPS];     // 1248 B -> total 21248 B -> 7 blocks/CU
  int blk = blockIdx.x;
  int g = blk & 63, sb = blk >> 6;
  int band = sb & 7, sig = sb >> 3;
  int tid = threadIdx.x;
  int wv = tid >> 6, ln = tid & 63;
  for (int idx = tid; idx < 2 * NHOPS; idx += 256) P[idx] = 0.0f;
  __syncthreads();
  int n1 = 4 * g + wv;
  size_t ibase = (size_t)(sig * NB + band) * L + (size_t)n1 * 625;
  float2* a = A + wv * 625;
  for (int k2 = ln; k2 < 625; k2 += 64) a[k2] = H[ibase + k2];
  dif625_s123<1>(a, ln, W);
  // stage 4 fused with energy: position 5q+r holds output n2 = 125r + rev3(q)
#pragma unroll
  for (int it = 0; it < 2; ++it) {
    int q = ln + it * 64;
    if (q < 125) {
      float2 v[5];
#pragma unroll
      for (int r = 0; r < 5; ++r) v[r] = a[5 * q + r];
      bf5s<1>(v);
      int revq = rev3_5(q);
#pragma unroll
      for (int r = 0; r < 5; ++r) {
        int h = (125 * r + revq) >> 2;
        atomicAdd(&P[h], v[r].x * v[r].x);
        atomicAdd(&P[NHOPS + h], v[r].y * v[r].y);
      }
    }
  }
  __syncthreads();
  int eb = (sig * NB + band) * NHOPS;
  for (int idx = tid; idx < 2 * NHOPS; idx += 256) {
    int comp = idx / NHOPS, h = idx - comp * NHOPS;
    atomicAdd(&E[comp * (BATCH * NB * NHOPS) + eb + h], P[idx]);
  }
}

// ---------- finalize: loudness, diff, softmax-weighted sum (1/N^2 folded in) ----------
__global__ __launch_bounds__(1024) void finalize_kernel(const float* __restrict__ E,
                                                        float* __restrict__ out) {
  constexpr int ND = BATCH * NB * NCHUNK;  // 9920
  constexpr float SC = (1.0f / 2048.0f) / ((float)L * (float)L);
  __shared__ float diffs[ND];
  __shared__ float sred[1024];
  int tid = threadIdx.x;
  for (int idx = tid; idx < ND; idx += 1024) {
    int sb = idx / NCHUNK;
    int k = idx - sb * NCHUNK;
    float msw = (E[sb * NHOPS + k] + E[sb * NHOPS + k + 1]) * SC;
    float mso = (E[64 * NHOPS + sb * NHOPS + k] + E[64 * NHOPS + sb * NHOPS + k + 1]) * SC;
    float lw = -0.691f + 10.0f * log10f(msw + 1e-12f);
    float lo = -0.691f + 10.0f * log10f(mso + 1e-12f);
    diffs[idx] = lw - lo;
  }
  __syncthreads();
  float mx = -3.4e38f;
  for (int idx = tid; idx < ND; idx += 1024) mx = fmaxf(mx, diffs[idx]);
  sred[tid] = mx;
  __syncthreads();
  for (int s = 512; s > 0; s >>= 1) {
    if (tid < s) sred[tid] = fmaxf(sred[tid], sred[tid + s]);
    __syncthreads();
  }
  float gmax = sred[0];
  __syncthreads();
  float se = 0.0f, swd = 0.0f;
  for (int idx = tid; idx < ND; idx += 1024) {
    float d = diffs[idx];
    float e = expf(d - gmax);
    se += e;
    swd += d * e;
  }
  sred[tid] = se; __syncthreads();
  for (int s = 512; s > 0; s >>= 1) { if (tid < s) sred[tid] += sred[tid + s]; __syncthreads(); }
  float tot = sred[0];
  __syncthreads();
  sred[tid] = swd; __syncthreads();
  for (int s = 512; s > 0; s >>= 1) { if (tid < s) sred[tid] += sred[tid + s]; __syncthreads(); }
  if (tid == 0) out[0] = sred[0] / tot;
}

extern "C" void kernel_launch(void* const* d_in, const int* in_sizes, int n_in,
                              void* d_out, int out_size, void* d_ws, size_t ws_size,
                              hipStream_t stream) {
  (void)in_sizes; (void)n_in; (void)out_size; (void)ws_size;
  char* ws = (char*)d_ws;
  float2* G = (float2*)ws;                        // 10,240,000 B
  float2* H = (float2*)(ws + 10240000);           // 81,920,000 B
  float*  E = (float*)(ws + 92160000);            // 79,872 B [2][64][156]
  float2* W = (float2*)(ws + 92240000);           // 1,280,000 B twiddles
  const float* w = (const float*)d_in[0];
  const float* o = (const float*)d_in[1];

  setup_kernel<<<dim3(625), dim3(256), 0, stream>>>(W);
  f1_kernel<<<dim3(BATCH * 64), dim3(256), 0, stream>>>(w, o, G, W);
  fi_kernel<<<dim3(BATCH * 157), dim3(256), 0, stream>>>(G, H, W);
  hipMemsetAsync(E, 0, 2 * BATCH * NB * NHOPS * sizeof(float), stream);
  i2_kernel<<<dim3(BATCH * NB * 64), dim3(256), 0, stream>>>(H, E, W);
  finalize_kernel<<<dim3(1), dim3(1024), 0, stream>>>(E, (float*)d_out);
}

// Round 5
// 194.226 us; speedup vs baseline: 1.4017x; 1.4017x over previous
//
#include <hip/hip_runtime.h>
#include <math.h>

// N = 160000 = 256 * 625; four-step FFT decomposition.
// f1: pack w+i*o, Stockham 625-FFT per column (ping-pong, sincosf), twiddle, -> G[k2][n1]
// f2: 256-FFT rows -> X[k2][k1] (bin 625*k1+k2)
// i1: mask band, inverse 256-FFT over k1, twiddle, -> H[n1][k2]
// i2: in-place DIF-625 (sign +) with whole-stage batched reads/writes (WAR-safe via
//     in-order per-wave DS), stage-1 fed straight from global; fused hop energies.
constexpr int L      = 160000;
constexpr int BATCH  = 8;
constexpr int NB     = 8;
constexpr int NHOPS  = 156;
constexpr int NCHUNK = 155;
constexpr float TWO_PI = 6.28318530717958647692f;

__device__ __forceinline__ float2 cmulf(float2 a, float2 b) {
  return make_float2(a.x * b.x - a.y * b.y, a.x * b.y + a.y * b.x);
}

template <int SIGN>
__device__ __forceinline__ float2 twld(const float2* __restrict__ W, int idx) {
  float2 t = W[idx];
  if constexpr (SIGN > 0) t.y = -t.y;
  return t;
}

template <int SIGN>
__device__ __forceinline__ void bf4s(float2* v) {
  float2 t0 = make_float2(v[0].x + v[2].x, v[0].y + v[2].y);
  float2 t1 = make_float2(v[0].x - v[2].x, v[0].y - v[2].y);
  float2 t2 = make_float2(v[1].x + v[3].x, v[1].y + v[3].y);
  float2 t3 = make_float2(v[1].x - v[3].x, v[1].y - v[3].y);
  v[0] = make_float2(t0.x + t2.x, t0.y + t2.y);
  v[2] = make_float2(t0.x - t2.x, t0.y - t2.y);
  if constexpr (SIGN < 0) {
    v[1] = make_float2(t1.x + t3.y, t1.y - t3.x);
    v[3] = make_float2(t1.x - t3.y, t1.y + t3.x);
  } else {
    v[1] = make_float2(t1.x - t3.y, t1.y + t3.x);
    v[3] = make_float2(t1.x + t3.y, t1.y - t3.x);
  }
}

template <int SIGN>
__device__ __forceinline__ void bf5s(float2* v) {
  const float c1 = 0.30901699437494745f, s1 = 0.9510565162951535f;
  const float c2 = -0.8090169943749475f, s2 = 0.5877852522924731f;
  float2 t1 = make_float2(v[1].x + v[4].x, v[1].y + v[4].y);
  float2 t3 = make_float2(v[1].x - v[4].x, v[1].y - v[4].y);
  float2 t2 = make_float2(v[2].x + v[3].x, v[2].y + v[3].y);
  float2 t4 = make_float2(v[2].x - v[3].x, v[2].y - v[3].y);
  float2 a = make_float2(v[0].x + c1 * t1.x + c2 * t2.x, v[0].y + c1 * t1.y + c2 * t2.y);
  float2 b = make_float2(s1 * t3.x + s2 * t4.x, s1 * t3.y + s2 * t4.y);
  float2 c = make_float2(v[0].x + c2 * t1.x + c1 * t2.x, v[0].y + c2 * t1.y + c1 * t2.y);
  float2 d = make_float2(s2 * t3.x - s1 * t4.x, s2 * t3.y - s1 * t4.y);
  v[0] = make_float2(v[0].x + t1.x + t2.x, v[0].y + t1.y + t2.y);
  if constexpr (SIGN < 0) {
    v[1] = make_float2(a.x + b.y, a.y - b.x);
    v[4] = make_float2(a.x - b.y, a.y + b.x);
    v[2] = make_float2(c.x + d.y, c.y - d.x);
    v[3] = make_float2(c.x - d.y, c.y + d.x);
  } else {
    v[1] = make_float2(a.x - b.y, a.y + b.x);
    v[4] = make_float2(a.x + b.y, a.y - b.x);
    v[2] = make_float2(c.x - d.y, c.y + d.x);
    v[3] = make_float2(c.x + d.y, c.y - d.x);
  }
}

template <int R>
__device__ __forceinline__ void twchain(float2* v, float2 t1) {
  float2 t = t1;
  v[1] = cmulf(v[1], t);
#pragma unroll
  for (int r = 2; r < R; ++r) { t = cmulf(t, t1); v[r] = cmulf(v[r], t); }
}

__device__ __forceinline__ int rev3_5(int q) {  // reverse 3 base-5 digits, q<125
  int q5 = q / 5, q25 = q / 25;
  int d0 = q - 5 * q5, d1 = q5 - 5 * q25;
  return 25 * d0 + 5 * d1 + q25;
}

// ---------- R2-style Stockham stage (sincosf twiddles, ping-pong buffers) ----------
template <int R, int Ns, int SIGN, int M>
__device__ __forceinline__ void lds_stage_sc(const float2* in, float2* out, int w) {
  constexpr int NR = M / R;
  for (int j = w; j < NR; j += 64) {
    float2 v[R];
#pragma unroll
    for (int r = 0; r < R; ++r) v[r] = in[j + r * NR];
    int jm = j % Ns;
    float base = (float)SIGN * (TWO_PI / (float)(Ns * R)) * (float)jm;
#pragma unroll
    for (int r = 1; r < R; ++r) {
      float s, c;
      __sincosf((float)r * base, &s, &c);
      v[r] = cmulf(v[r], make_float2(c, s));
    }
    if constexpr (R == 4) bf4s<SIGN>(v); else bf5s<SIGN>(v);
    int od = (j / Ns) * (Ns * R) + jm;
#pragma unroll
    for (int r = 0; r < R; ++r) out[od + r * Ns] = v[r];
  }
}

template <int SIGN>
__device__ __forceinline__ void fft625_sc(float2* a, float2* b, int w) {
  lds_stage_sc<5, 1, SIGN, 625>(a, b, w);   __syncthreads();
  lds_stage_sc<5, 5, SIGN, 625>(b, a, w);   __syncthreads();
  lds_stage_sc<5, 25, SIGN, 625>(a, b, w);  __syncthreads();
  lds_stage_sc<5, 125, SIGN, 625>(b, a, w); __syncthreads();  // result in a
}

template <int SIGN>
__device__ __forceinline__ void fft256_sc(float2* a, float2* b, int w) {
  lds_stage_sc<4, 1, SIGN, 256>(a, b, w);   __syncthreads();
  lds_stage_sc<4, 4, SIGN, 256>(b, a, w);   __syncthreads();
  lds_stage_sc<4, 16, SIGN, 256>(a, b, w);  __syncthreads();
  lds_stage_sc<4, 64, SIGN, 256>(b, a, w);  __syncthreads();  // result in a
}

// ---------- setup: W[k] = e^{-2pi i k/L} (used by i2 only) ----------
__global__ __launch_bounds__(256) void setup_kernel(float2* __restrict__ W) {
  int k = blockIdx.x * 256 + threadIdx.x;
  if (k < L) {
    float s, c;
    sincosf(-TWO_PI * ((float)k / (float)L), &s, &c);
    W[k] = make_float2(c, s);
  }
}

// ---------- F1 (R2): pack w+i*o, 625-FFT columns, twiddle, store [k2][n1] ----------
__global__ __launch_bounds__(256) void f1_kernel(const float* __restrict__ win,
                                                 const float* __restrict__ oin,
                                                 float2* __restrict__ G) {
  __shared__ float2 A[4 * 625], B[4 * 625];
  int blk = blockIdx.x;
  int sig = blk >> 6, g = blk & 63;
  int n1base = g * 4;
  int tid = threadIdx.x;
  const float* wp = win + (size_t)sig * L;
  const float* op = oin + (size_t)sig * L;
  for (int idx = tid; idx < 2500; idx += 256) {
    int r = idx >> 2, cc = idx & 3;
    int n = (r << 8) + n1base + cc;
    A[cc * 625 + r] = make_float2(wp[n], op[n]);
  }
  __syncthreads();
  int wv = tid >> 6, ln = tid & 63;
  fft625_sc<-1>(A + wv * 625, B + wv * 625, ln);
  for (int idx = tid; idx < 2500; idx += 256) {
    int k2 = idx >> 2, cc = idx & 3;
    int n1 = n1base + cc;
    float ang = -(TWO_PI / (float)L) * (float)(n1 * k2);
    float s, c;
    __sincosf(ang, &s, &c);
    G[(size_t)sig * L + k2 * 256 + n1] = cmulf(A[cc * 625 + k2], make_float2(c, s));
  }
}

// ---------- F2 (R2): 256-FFT rows -> X[k2][k1] ----------
__global__ __launch_bounds__(256) void f2_kernel(const float2* __restrict__ G,
                                                 float2* __restrict__ X) {
  __shared__ float2 A[4 * 257], B[4 * 257];
  int blk = blockIdx.x;
  int sig = blk / 157, gr = blk % 157;
  int k2base = gr * 4;
  int tid = threadIdx.x;
  for (int idx = tid; idx < 1024; idx += 256) {
    int row = idx >> 8, k1 = idx & 255;
    int k2 = k2base + row;
    if (k2 < 625) A[row * 257 + k1] = G[(size_t)sig * L + k2 * 256 + k1];
  }
  __syncthreads();
  int wv = tid >> 6, ln = tid & 63;
  fft256_sc<-1>(A + wv * 257, B + wv * 257, ln);
  for (int idx = tid; idx < 1024; idx += 256) {
    int row = idx >> 8, k1 = idx & 255;
    int k2 = k2base + row;
    if (k2 < 625) X[(size_t)sig * L + k2 * 256 + k1] = A[row * 257 + k1];
  }
}

// ---------- I1 (R2): mask inline, inverse 256-FFT over k1, twiddle, -> H[n1][k2] ----------
__global__ __launch_bounds__(256) void i1_kernel(const float2* __restrict__ X,
                                                 float2* __restrict__ H) {
  __shared__ float2 A[4 * 257], B[4 * 257];
  int blk = blockIdx.x;
  int gr = blk % 157, sb = blk / 157;
  int band = sb & 7, sig = sb >> 3;
  int k2base = gr * 4;
  int tid = threadIdx.x;
  for (int idx = tid; idx < 1024; idx += 256) {
    int row = idx >> 8, k1 = idx & 255;
    int k2 = k2base + row;
    if (k2 < 625) {
      int bin = 625 * k1 + k2;
      int m = min(bin, L - bin);
      int b = (m == 0) ? (NB - 1) : (m - 1) / 10000;
      float2 x = make_float2(0.0f, 0.0f);
      if (b == band) x = X[(size_t)sig * L + k2 * 256 + k1];
      A[row * 257 + k1] = x;
    }
  }
  __syncthreads();
  int wv = tid >> 6, ln = tid & 63;
  fft256_sc<1>(A + wv * 257, B + wv * 257, ln);
  size_t obase = (size_t)(sig * NB + band) * L;
  for (int idx = tid; idx < 1024; idx += 256) {
    int cc = idx & 3, n1 = idx >> 2;
    int k2 = k2base + cc;
    if (k2 < 625) {
      float ang = (TWO_PI / (float)L) * (float)(n1 * k2);
      float s, c;
      __sincosf(ang, &s, &c);
      H[obase + (size_t)n1 * 625 + k2] = cmulf(A[cc * 257 + n1], make_float2(c, s));
    }
  }
}

// ---------- i2 in-place stage (stages 2,3): ALL reads of both butterflies issued
// before ANY write -> in-order per-wave DS makes in-place WAR-safe, no extra waits.
template <int SUB, int STEP>
__device__ __forceinline__ void i2_stage(float2* a, int ln, const float2* __restrict__ W) {
  int i1 = ln, i2 = ln + 64;
  bool g2 = (i2 < 125);
  int b1 = (i1 / SUB) * (5 * SUB) + (i1 % SUB);
  int b2 = (i2 / SUB) * (5 * SUB) + (i2 % SUB);
  float2 u[5], v[5];
#pragma unroll
  for (int r = 0; r < 5; ++r) u[r] = a[b1 + SUB * r];
  if (g2) {
#pragma unroll
    for (int r = 0; r < 5; ++r) v[r] = a[b2 + SUB * r];
  }
  bf5s<1>(u);
  twchain<5>(u, twld<1>(W, (i1 % SUB) * STEP));
  if (g2) {
    bf5s<1>(v);
    twchain<5>(v, twld<1>(W, (i2 % SUB) * STEP));
  }
#pragma unroll
  for (int r = 0; r < 5; ++r) a[b1 + SUB * r] = u[r];
  if (g2) {
#pragma unroll
    for (int r = 0; r < 5; ++r) a[b2 + SUB * r] = v[r];
  }
}

// ---------- I2: in-place DIF-625 (sign +), stage 1 from global, fused hop energies ----------
__global__ __launch_bounds__(256) void i2_kernel(const float2* __restrict__ H,
                                                 float* __restrict__ E,
                                                 const float2* __restrict__ W) {
  __shared__ float2 A[4 * 625];      // 20000 B
  __shared__ float P[2 * NHOPS];     // 1248 B -> 21248 B total -> 7 blocks/CU
  int blk = blockIdx.x;
  int g = blk & 63, sb = blk >> 6;
  int band = sb & 7, sig = sb >> 3;
  int tid = threadIdx.x;
  int wv = tid >> 6, ln = tid & 63;
  for (int idx = tid; idx < 2 * NHOPS; idx += 256) P[idx] = 0.0f;
  __syncthreads();
  int n1 = 4 * g + wv;
  const float2* Hc = H + (size_t)(sig * NB + band) * L + (size_t)n1 * 625;
  float2* a = A + wv * 625;

  // stage 1: read straight from global (coalesced per r-batch), butterfly, write LDS
  {
    int j1 = ln, j2 = ln + 64;
    bool g2 = (j2 < 125);
    float2 u[5], v[5];
#pragma unroll
    for (int r = 0; r < 5; ++r) u[r] = Hc[j1 + 125 * r];
    if (g2) {
#pragma unroll
      for (int r = 0; r < 5; ++r) v[r] = Hc[j2 + 125 * r];
    }
    bf5s<1>(u);
    twchain<5>(u, twld<1>(W, j1 * 256));
    if (g2) {
      bf5s<1>(v);
      twchain<5>(v, twld<1>(W, j2 * 256));
    }
#pragma unroll
    for (int r = 0; r < 5; ++r) a[j1 + 125 * r] = u[r];
    if (g2) {
#pragma unroll
      for (int r = 0; r < 5; ++r) a[j2 + 125 * r] = v[r];
    }
  }
  i2_stage<25, 1280>(a, ln, W);
  i2_stage<5, 6400>(a, ln, W);
  // stage 4: batched reads, butterfly, scatter to NATURAL order n2 = 125r + rev3(q)
  {
    int q1 = ln, q2 = ln + 64;
    bool g2 = (q2 < 125);
    float2 u[5], v[5];
#pragma unroll
    for (int r = 0; r < 5; ++r) u[r] = a[5 * q1 + r];
    if (g2) {
#pragma unroll
      for (int r = 0; r < 5; ++r) v[r] = a[5 * q2 + r];
    }
    bf5s<1>(u);
    if (g2) bf5s<1>(v);
    int rv1 = rev3_5(q1), rv2 = rev3_5(q2);
#pragma unroll
    for (int r = 0; r < 5; ++r) a[125 * r + rv1] = u[r];
    if (g2) {
#pragma unroll
      for (int r = 0; r < 5; ++r) a[125 * r + rv2] = v[r];
    }
  }
  // energy: a[n2] = L*(w_band + i*o_band) at n = 256*n2 + n1; hop h = n2>>2
  for (int h = ln; h < NHOPS; h += 64) {
    float ex = 0.0f, ey = 0.0f;
#pragma unroll
    for (int d = 0; d < 4; ++d) {
      float2 z = a[4 * h + d];
      ex += z.x * z.x;
      ey += z.y * z.y;
    }
    atomicAdd(&P[h], ex);
    atomicAdd(&P[NHOPS + h], ey);
  }
  __syncthreads();
  int eb = (sig * NB + band) * NHOPS;
  for (int idx = tid; idx < 2 * NHOPS; idx += 256) {
    int comp = idx / NHOPS, h = idx - comp * NHOPS;
    atomicAdd(&E[comp * (BATCH * NB * NHOPS) + eb + h], P[idx]);
  }
}

// ---------- finalize: loudness, diff, softmax-weighted sum (1/L^2 folded into SC) ----------
__global__ __launch_bounds__(1024) void finalize_kernel(const float* __restrict__ E,
                                                        float* __restrict__ out) {
  constexpr int ND = BATCH * NB * NCHUNK;  // 9920
  constexpr float SC = (1.0f / 2048.0f) / ((float)L * (float)L);
  __shared__ float diffs[ND];
  __shared__ float sred[1024];
  int tid = threadIdx.x;
  for (int idx = tid; idx < ND; idx += 1024) {
    int sb = idx / NCHUNK;
    int k = idx - sb * NCHUNK;
    float msw = (E[sb * NHOPS + k] + E[sb * NHOPS + k + 1]) * SC;
    float mso = (E[64 * NHOPS + sb * NHOPS + k] + E[64 * NHOPS + sb * NHOPS + k + 1]) * SC;
    float lw = -0.691f + 10.0f * log10f(msw + 1e-12f);
    float lo = -0.691f + 10.0f * log10f(mso + 1e-12f);
    diffs[idx] = lw - lo;
  }
  __syncthreads();
  float mx = -3.4e38f;
  for (int idx = tid; idx < ND; idx += 1024) mx = fmaxf(mx, diffs[idx]);
  sred[tid] = mx;
  __syncthreads();
  for (int s = 512; s > 0; s >>= 1) {
    if (tid < s) sred[tid] = fmaxf(sred[tid], sred[tid + s]);
    __syncthreads();
  }
  float gmax = sred[0];
  __syncthreads();
  float se = 0.0f, swd = 0.0f;
  for (int idx = tid; idx < ND; idx += 1024) {
    float d = diffs[idx];
    float e = expf(d - gmax);
    se += e;
    swd += d * e;
  }
  sred[tid] = se; __syncthreads();
  for (int s = 512; s > 0; s >>= 1) { if (tid < s) sred[tid] += sred[tid + s]; __syncthreads(); }
  float tot = sred[0];
  __syncthreads();
  sred[tid] = swd; __syncthreads();
  for (int s = 512; s > 0; s >>= 1) { if (tid < s) sred[tid] += sred[tid + s]; __syncthreads(); }
  if (tid == 0) out[0] = sred[0] / tot;
}

extern "C" void kernel_launch(void* const* d_in, const int* in_sizes, int n_in,
                              void* d_out, int out_size, void* d_ws, size_t ws_size,
                              hipStream_t stream) {
  (void)in_sizes; (void)n_in; (void)out_size; (void)ws_size;
  char* ws = (char*)d_ws;
  float2* G = (float2*)ws;                        // 10,240,000 B
  float2* X = (float2*)(ws + 10240000);           // 10,240,000 B
  float2* H = (float2*)(ws + 20480000);           // 81,920,000 B
  float*  E = (float*)(ws + 102400000);           // 79,872 B [2][64][156]
  float2* W = (float2*)(ws + 102480000);          // 1,280,000 B twiddles (i2 only)
  const float* w = (const float*)d_in[0];
  const float* o = (const float*)d_in[1];

  setup_kernel<<<dim3(625), dim3(256), 0, stream>>>(W);
  f1_kernel<<<dim3(BATCH * 64), dim3(256), 0, stream>>>(w, o, G);
  f2_kernel<<<dim3(BATCH * 157), dim3(256), 0, stream>>>(G, X);
  i1_kernel<<<dim3(BATCH * NB * 157), dim3(256), 0, stream>>>(X, H);
  hipMemsetAsync(E, 0, 2 * BATCH * NB * NHOPS * sizeof(float), stream);
  i2_kernel<<<dim3(BATCH * NB * 64), dim3(256), 0, stream>>>(H, E, W);
  finalize_kernel<<<dim3(1), dim3(1024), 0, stream>>>(E, (float*)d_out);
}

// Round 6
// 193.893 us; speedup vs baseline: 1.4041x; 1.0017x over previous
//
#include <hip/hip_runtime.h>
#include <math.h>

// N = 160000 = 256 * 625; four-step FFT decomposition.
// f1: pack w+i*o, Stockham 625-FFT per column (ping-pong, sincosf), twiddle, -> G[k2][n1]
// f2: 256-FFT rows -> X[k2][k1] (bin 625*k1+k2)
// i1: SPARSE band load (two <=16-run k1 arcs), inverse 256-FFT over k1, twiddle, -> H[n1][k2]
// i2: in-place DIF-625 (sign +), column split across 2 waves (512-thr blocks, per-stage
//     barriers), stage-1 fed straight from global; fused hop energies.
constexpr int L      = 160000;
constexpr int BATCH  = 8;
constexpr int NB     = 8;
constexpr int NHOPS  = 156;
constexpr int NCHUNK = 155;
constexpr float TWO_PI = 6.28318530717958647692f;

__device__ __forceinline__ float2 cmulf(float2 a, float2 b) {
  return make_float2(a.x * b.x - a.y * b.y, a.x * b.y + a.y * b.x);
}

template <int SIGN>
__device__ __forceinline__ float2 twld(const float2* __restrict__ W, int idx) {
  float2 t = W[idx];
  if constexpr (SIGN > 0) t.y = -t.y;
  return t;
}

template <int SIGN>
__device__ __forceinline__ void bf4s(float2* v) {
  float2 t0 = make_float2(v[0].x + v[2].x, v[0].y + v[2].y);
  float2 t1 = make_float2(v[0].x - v[2].x, v[0].y - v[2].y);
  float2 t2 = make_float2(v[1].x + v[3].x, v[1].y + v[3].y);
  float2 t3 = make_float2(v[1].x - v[3].x, v[1].y - v[3].y);
  v[0] = make_float2(t0.x + t2.x, t0.y + t2.y);
  v[2] = make_float2(t0.x - t2.x, t0.y - t2.y);
  if constexpr (SIGN < 0) {
    v[1] = make_float2(t1.x + t3.y, t1.y - t3.x);
    v[3] = make_float2(t1.x - t3.y, t1.y + t3.x);
  } else {
    v[1] = make_float2(t1.x - t3.y, t1.y + t3.x);
    v[3] = make_float2(t1.x + t3.y, t1.y - t3.x);
  }
}

template <int SIGN>
__device__ __forceinline__ void bf5s(float2* v) {
  const float c1 = 0.30901699437494745f, s1 = 0.9510565162951535f;
  const float c2 = -0.8090169943749475f, s2 = 0.5877852522924731f;
  float2 t1 = make_float2(v[1].x + v[4].x, v[1].y + v[4].y);
  float2 t3 = make_float2(v[1].x - v[4].x, v[1].y - v[4].y);
  float2 t2 = make_float2(v[2].x + v[3].x, v[2].y + v[3].y);
  float2 t4 = make_float2(v[2].x - v[3].x, v[2].y - v[3].y);
  float2 a = make_float2(v[0].x + c1 * t1.x + c2 * t2.x, v[0].y + c1 * t1.y + c2 * t2.y);
  float2 b = make_float2(s1 * t3.x + s2 * t4.x, s1 * t3.y + s2 * t4.y);
  float2 c = make_float2(v[0].x + c2 * t1.x + c1 * t2.x, v[0].y + c2 * t1.y + c1 * t2.y);
  float2 d = make_float2(s2 * t3.x - s1 * t4.x, s2 * t3.y - s1 * t4.y);
  v[0] = make_float2(v[0].x + t1.x + t2.x, v[0].y + t1.y + t2.y);
  if constexpr (SIGN < 0) {
    v[1] = make_float2(a.x + b.y, a.y - b.x);
    v[4] = make_float2(a.x - b.y, a.y + b.x);
    v[2] = make_float2(c.x + d.y, c.y - d.x);
    v[3] = make_float2(c.x - d.y, c.y + d.x);
  } else {
    v[1] = make_float2(a.x - b.y, a.y + b.x);
    v[4] = make_float2(a.x + b.y, a.y - b.x);
    v[2] = make_float2(c.x - d.y, c.y + d.x);
    v[3] = make_float2(c.x + d.y, c.y - d.x);
  }
}

template <int R>
__device__ __forceinline__ void twchain(float2* v, float2 t1) {
  float2 t = t1;
  v[1] = cmulf(v[1], t);
#pragma unroll
  for (int r = 2; r < R; ++r) { t = cmulf(t, t1); v[r] = cmulf(v[r], t); }
}

__device__ __forceinline__ int rev3_5(int q) {  // reverse 3 base-5 digits, q<125
  int q5 = q / 5, q25 = q / 25;
  int d0 = q - 5 * q5, d1 = q5 - 5 * q25;
  return 25 * d0 + 5 * d1 + q25;
}

// ---------- R2-style Stockham stage (sincosf twiddles, ping-pong buffers) ----------
template <int R, int Ns, int SIGN, int M>
__device__ __forceinline__ void lds_stage_sc(const float2* in, float2* out, int w) {
  constexpr int NR = M / R;
  for (int j = w; j < NR; j += 64) {
    float2 v[R];
#pragma unroll
    for (int r = 0; r < R; ++r) v[r] = in[j + r * NR];
    int jm = j % Ns;
    float base = (float)SIGN * (TWO_PI / (float)(Ns * R)) * (float)jm;
#pragma unroll
    for (int r = 1; r < R; ++r) {
      float s, c;
      __sincosf((float)r * base, &s, &c);
      v[r] = cmulf(v[r], make_float2(c, s));
    }
    if constexpr (R == 4) bf4s<SIGN>(v); else bf5s<SIGN>(v);
    int od = (j / Ns) * (Ns * R) + jm;
#pragma unroll
    for (int r = 0; r < R; ++r) out[od + r * Ns] = v[r];
  }
}

template <int SIGN>
__device__ __forceinline__ void fft625_sc(float2* a, float2* b, int w) {
  lds_stage_sc<5, 1, SIGN, 625>(a, b, w);   __syncthreads();
  lds_stage_sc<5, 5, SIGN, 625>(b, a, w);   __syncthreads();
  lds_stage_sc<5, 25, SIGN, 625>(a, b, w);  __syncthreads();
  lds_stage_sc<5, 125, SIGN, 625>(b, a, w); __syncthreads();  // result in a
}

template <int SIGN>
__device__ __forceinline__ void fft256_sc(float2* a, float2* b, int w) {
  lds_stage_sc<4, 1, SIGN, 256>(a, b, w);   __syncthreads();
  lds_stage_sc<4, 4, SIGN, 256>(b, a, w);   __syncthreads();
  lds_stage_sc<4, 16, SIGN, 256>(a, b, w);  __syncthreads();
  lds_stage_sc<4, 64, SIGN, 256>(b, a, w);  __syncthreads();  // result in a
}

// ---------- setup: W[k] = e^{-2pi i k/L} (used by i2 only) ----------
__global__ __launch_bounds__(256) void setup_kernel(float2* __restrict__ W) {
  int k = blockIdx.x * 256 + threadIdx.x;
  if (k < L) {
    float s, c;
    sincosf(-TWO_PI * ((float)k / (float)L), &s, &c);
    W[k] = make_float2(c, s);
  }
}

// ---------- F1 (R2): pack w+i*o, 625-FFT columns, twiddle, store [k2][n1] ----------
__global__ __launch_bounds__(256) void f1_kernel(const float* __restrict__ win,
                                                 const float* __restrict__ oin,
                                                 float2* __restrict__ G) {
  __shared__ float2 A[4 * 625], B[4 * 625];
  int blk = blockIdx.x;
  int sig = blk >> 6, g = blk & 63;
  int n1base = g * 4;
  int tid = threadIdx.x;
  const float* wp = win + (size_t)sig * L;
  const float* op = oin + (size_t)sig * L;
  for (int idx = tid; idx < 2500; idx += 256) {
    int r = idx >> 2, cc = idx & 3;
    int n = (r << 8) + n1base + cc;
    A[cc * 625 + r] = make_float2(wp[n], op[n]);
  }
  __syncthreads();
  int wv = tid >> 6, ln = tid & 63;
  fft625_sc<-1>(A + wv * 625, B + wv * 625, ln);
  for (int idx = tid; idx < 2500; idx += 256) {
    int k2 = idx >> 2, cc = idx & 3;
    int n1 = n1base + cc;
    float ang = -(TWO_PI / (float)L) * (float)(n1 * k2);
    float s, c;
    __sincosf(ang, &s, &c);
    G[(size_t)sig * L + k2 * 256 + n1] = cmulf(A[cc * 625 + k2], make_float2(c, s));
  }
}

// ---------- F2 (R2): 256-FFT rows -> X[k2][k1] ----------
__global__ __launch_bounds__(256) void f2_kernel(const float2* __restrict__ G,
                                                 float2* __restrict__ X) {
  __shared__ float2 A[4 * 257], B[4 * 257];
  int blk = blockIdx.x;
  int sig = blk / 157, gr = blk % 157;
  int k2base = gr * 4;
  int tid = threadIdx.x;
  for (int idx = tid; idx < 1024; idx += 256) {
    int row = idx >> 8, k1 = idx & 255;
    int k2 = k2base + row;
    if (k2 < 625) A[row * 257 + k1] = G[(size_t)sig * L + k2 * 256 + k1];
  }
  __syncthreads();
  int wv = tid >> 6, ln = tid & 63;
  fft256_sc<-1>(A + wv * 257, B + wv * 257, ln);
  for (int idx = tid; idx < 1024; idx += 256) {
    int row = idx >> 8, k1 = idx & 255;
    int k2 = k2base + row;
    if (k2 < 625) X[(size_t)sig * L + k2 * 256 + k1] = A[row * 257 + k1];
  }
}

// ---------- I1: SPARSE band load, inverse 256-FFT over k1, twiddle, -> H[n1][k2] ----------
// Band b nonzero bins: m = min(k, L-k) in [10^4 b + 1, 10^4 (b+1)] (+ k=0 for b=7):
//   arc1: k in [10^4 b + 1, 10^4 (b+1)]          (b=7: [70001, 80000])
//   arc2: k in [L - 10^4(b+1), L - 10^4 b - 1]   (b=7: [80001, 89999])
// For fixed k2 (k = 625 k1 + k2), each arc is <=16 CONSECUTIVE k1 values.
__global__ __launch_bounds__(256) void i1_kernel(const float2* __restrict__ X,
                                                 float2* __restrict__ H) {
  __shared__ float2 A[4 * 257], B[4 * 257];
  int blk = blockIdx.x;
  int gr = blk % 157, sb = blk / 157;
  int band = sb & 7, sig = sb >> 3;
  int k2base = gr * 4;
  int tid = threadIdx.x;
  int wv = tid >> 6, ln = tid & 63;
  int k2 = k2base + wv;
  {
    float2* row = A + wv * 257;
    float2 zero = make_float2(0.0f, 0.0f);
    for (int k1 = ln; k1 < 256; k1 += 64) row[k1] = zero;   // same wave: DS in-order
    if (k2 < 625) {
      int lo1, hi1, lo2, hi2;
      if (band < 7) {
        lo1 = 10000 * band + 1;        hi1 = 10000 * (band + 1);
        lo2 = L - 10000 * (band + 1);  hi2 = L - 10000 * band - 1;
      } else {
        lo1 = 70001; hi1 = 80000; lo2 = 80001; hi2 = 89999;
      }
      const float2* Xr = X + (size_t)sig * L + k2 * 256;
      int s1 = (lo1 - k2 + 624) / 625;
      int e1 = (hi1 - k2) / 625; if (e1 > 255) e1 = 255;
      int s2 = (lo2 - k2 + 624) / 625;
      int e2 = (hi2 - k2) / 625; if (e2 > 255) e2 = 255;
      int c1 = e1 - s1 + 1;
      int c2 = e2 - s2 + 1;
      if (ln < c1) { int k1 = s1 + ln; row[k1] = Xr[k1]; }
      int l2 = ln - 32;
      if (l2 >= 0 && l2 < c2) { int k1 = s2 + l2; row[k1] = Xr[k1]; }
      if (band == 7 && k2 == 0 && ln == 0) row[0] = Xr[0];   // DC bin -> band 7
    }
  }
  __syncthreads();
  fft256_sc<1>(A + wv * 257, B + wv * 257, ln);
  size_t obase = (size_t)(sig * NB + band) * L;
  for (int idx = tid; idx < 1024; idx += 256) {
    int cc = idx & 3, n1 = idx >> 2;
    int k2e = k2base + cc;
    if (k2e < 625) {
      float ang = (TWO_PI / (float)L) * (float)(n1 * k2e);
      float s, c;
      __sincosf(ang, &s, &c);
      H[obase + (size_t)n1 * 625 + k2e] = cmulf(A[cc * 257 + n1], make_float2(c, s));
    }
  }
}

// ---------- I2: in-place DIF-625 (sign +), 2 waves per column, fused hop energies ----------
__global__ __launch_bounds__(512) void i2_kernel(const float2* __restrict__ H,
                                                 float* __restrict__ E,
                                                 const float2* __restrict__ W) {
  __shared__ float2 A[4 * 625];      // 20000 B
  __shared__ float P[2 * NHOPS];     // 1248 B -> 21248 B; 512 thr -> 4 blocks/CU = 32 waves
  int blk = blockIdx.x;
  int g = blk & 63, sb = blk >> 6;
  int band = sb & 7, sig = sb >> 3;
  int tid = threadIdx.x;
  int col = tid >> 7;                 // 4 columns, 2 waves (128 threads) each
  int j = tid & 127;                  // butterfly index within column, <125 active
  bool act = (j < 125);
  for (int idx = tid; idx < 2 * NHOPS; idx += 512) P[idx] = 0.0f;
  int n1 = 4 * g + col;
  const float2* Hc = H + (size_t)(sig * NB + band) * L + (size_t)n1 * 625;
  float2* a = A + col * 625;

  // stage 1: global -> LDS (stride 125, tw W625^{j r} step 256)
  if (act) {
    float2 u[5];
#pragma unroll
    for (int r = 0; r < 5; ++r) u[r] = Hc[j + 125 * r];
    bf5s<1>(u);
    twchain<5>(u, twld<1>(W, j * 256));
#pragma unroll
    for (int r = 0; r < 5; ++r) a[j + 125 * r] = u[r];
  }
  __syncthreads();
  // stage 2: stride 25, tw W125^{(j%25) r} step 1280
  if (act) {
    int b1 = (j / 25) * 125 + (j % 25);
    float2 u[5];
#pragma unroll
    for (int r = 0; r < 5; ++r) u[r] = a[b1 + 25 * r];
    bf5s<1>(u);
    twchain<5>(u, twld<1>(W, (j % 25) * 1280));
#pragma unroll
    for (int r = 0; r < 5; ++r) a[b1 + 25 * r] = u[r];
  }
  __syncthreads();
  // stage 3: stride 5, tw W25^{(j%5) r} step 6400
  if (act) {
    int b1 = (j / 5) * 25 + (j % 5);
    float2 u[5];
#pragma unroll
    for (int r = 0; r < 5; ++r) u[r] = a[b1 + 5 * r];
    bf5s<1>(u);
    twchain<5>(u, twld<1>(W, (j % 5) * 6400));
#pragma unroll
    for (int r = 0; r < 5; ++r) a[b1 + 5 * r] = u[r];
  }
  __syncthreads();
  // stage 4: stride 1, no twiddle, scatter to NATURAL order n2 = 125 r + rev3(j)
  if (act) {
    float2 u[5];
#pragma unroll
    for (int r = 0; r < 5; ++r) u[r] = a[5 * j + r];
    bf5s<1>(u);
    int rv = rev3_5(j);
#pragma unroll
    for (int r = 0; r < 5; ++r) a[125 * r + rv] = u[r];
  }
  __syncthreads();
  // energy: a[n2] = L*(w_band + i*o_band) at n = 256*n2 + n1; hop h sums n2 in [4h,4h+4)
  for (int t = tid; t < 4 * NHOPS; t += 512) {
    int c = t / NHOPS, h = t - c * NHOPS;
    const float2* S = A + c * 625 + 4 * h;
    float ex = 0.0f, ey = 0.0f;
#pragma unroll
    for (int d = 0; d < 4; ++d) {
      float2 z = S[d];
      ex += z.x * z.x;
      ey += z.y * z.y;
    }
    atomicAdd(&P[h], ex);
    atomicAdd(&P[NHOPS + h], ey);
  }
  __syncthreads();
  int eb = (sig * NB + band) * NHOPS;
  for (int idx = tid; idx < 2 * NHOPS; idx += 512) {
    int comp = idx / NHOPS, h = idx - comp * NHOPS;
    atomicAdd(&E[comp * (BATCH * NB * NHOPS) + eb + h], P[idx]);
  }
}

// ---------- finalize: loudness, diff, softmax-weighted sum (1/L^2 folded into SC) ----------
__global__ __launch_bounds__(1024) void finalize_kernel(const float* __restrict__ E,
                                                        float* __restrict__ out) {
  constexpr int ND = BATCH * NB * NCHUNK;  // 9920
  constexpr float SC = (1.0f / 2048.0f) / ((float)L * (float)L);
  __shared__ float diffs[ND];
  __shared__ float sred[1024];
  int tid = threadIdx.x;
  for (int idx = tid; idx < ND; idx += 1024) {
    int sb = idx / NCHUNK;
    int k = idx - sb * NCHUNK;
    float msw = (E[sb * NHOPS + k] + E[sb * NHOPS + k + 1]) * SC;
    float mso = (E[64 * NHOPS + sb * NHOPS + k] + E[64 * NHOPS + sb * NHOPS + k + 1]) * SC;
    float lw = -0.691f + 10.0f * log10f(msw + 1e-12f);
    float lo = -0.691f + 10.0f * log10f(mso + 1e-12f);
    diffs[idx] = lw - lo;
  }
  __syncthreads();
  float mx = -3.4e38f;
  for (int idx = tid; idx < ND; idx += 1024) mx = fmaxf(mx, diffs[idx]);
  sred[tid] = mx;
  __syncthreads();
  for (int s = 512; s > 0; s >>= 1) {
    if (tid < s) sred[tid] = fmaxf(sred[tid], sred[tid + s]);
    __syncthreads();
  }
  float gmax = sred[0];
  __syncthreads();
  float se = 0.0f, swd = 0.0f;
  for (int idx = tid; idx < ND; idx += 1024) {
    float d = diffs[idx];
    float e = expf(d - gmax);
    se += e;
    swd += d * e;
  }
  sred[tid] = se; __syncthreads();
  for (int s = 512; s > 0; s >>= 1) { if (tid < s) sred[tid] += sred[tid + s]; __syncthreads(); }
  float tot = sred[0];
  __syncthreads();
  sred[tid] = swd; __syncthreads();
  for (int s = 512; s > 0; s >>= 1) { if (tid < s) sred[tid] += sred[tid + s]; __syncthreads(); }
  if (tid == 0) out[0] = sred[0] / tot;
}

extern "C" void kernel_launch(void* const* d_in, const int* in_sizes, int n_in,
                              void* d_out, int out_size, void* d_ws, size_t ws_size,
                              hipStream_t stream) {
  (void)in_sizes; (void)n_in; (void)out_size; (void)ws_size;
  char* ws = (char*)d_ws;
  float2* G = (float2*)ws;                        // 10,240,000 B
  float2* X = (float2*)(ws + 10240000);           // 10,240,000 B
  float2* H = (float2*)(ws + 20480000);           // 81,920,000 B
  float*  E = (float*)(ws + 102400000);           // 79,872 B [2][64][156]
  float2* W = (float2*)(ws + 102480000);          // 1,280,000 B twiddles (i2 only)
  const float* w = (const float*)d_in[0];
  const float* o = (const float*)d_in[1];

  setup_kernel<<<dim3(625), dim3(256), 0, stream>>>(W);
  f1_kernel<<<dim3(BATCH * 64), dim3(256), 0, stream>>>(w, o, G);
  f2_kernel<<<dim3(BATCH * 157), dim3(256), 0, stream>>>(G, X);
  i1_kernel<<<dim3(BATCH * NB * 157), dim3(256), 0, stream>>>(X, H);
  hipMemsetAsync(E, 0, 2 * BATCH * NB * NHOPS * sizeof(float), stream);
  i2_kernel<<<dim3(BATCH * NB * 64), dim3(512), 0, stream>>>(H, E, W);
  finalize_kernel<<<dim3(1), dim3(1024), 0, stream>>>(E, (float*)d_out);
}